// Round 1
// baseline (106.298 us; speedup 1.0000x reference)
//
#include <hip/hip_runtime.h>
#include <math.h>

#define B_ 2048
#define D_ 512
#define H_ 512
#define A_ 18
#define T_ 16
#define MT 16            // samples per tile
#define MAXTILES 144     // sum ceil(cnt_t/MT) <= B/MT + T = 128+16

// ws int layout:
// [0]        tile_total
// [1..17)    counts[T]
// [17..34)   offsets[T+1]
// [34..50)   cursor[T]
// [50..194)  tiles[MAXTILES]  (t<<16 | tile_idx)
// [256..2304) order[B]

__global__ void nk_init(int* wsi) {
    int i = threadIdx.x;
    if (i < 50) wsi[i] = 0;
}

__global__ void nk_count(const int* task_id, int* wsi) {
    int b = blockIdx.x * blockDim.x + threadIdx.x;
    if (b < B_) atomicAdd(&wsi[1 + task_id[b]], 1);
}

__global__ void nk_plan(int* wsi) {
    // single thread: prefix sum + tile list
    int off = 0, tot = 0;
    for (int t = 0; t < T_; ++t) {
        wsi[17 + t] = off;
        int cnt = wsi[1 + t];
        int nt = (cnt + MT - 1) / MT;
        for (int k = 0; k < nt; ++k) wsi[50 + tot++] = (t << 16) | k;
        off += cnt;
    }
    wsi[17 + T_] = off;   // == B_
    wsi[0] = tot;
}

__global__ void nk_scatter(const int* task_id, int* wsi) {
    int b = blockIdx.x * blockDim.x + threadIdx.x;
    if (b < B_) {
        int t = task_id[b];
        int pos = atomicAdd(&wsi[34 + t], 1);
        wsi[256 + wsi[17 + t] + pos] = b;
    }
}

__global__ __launch_bounds__(512) void nk_main(
        const float* __restrict__ xs, const float* __restrict__ W1,
        const float* __restrict__ b1, const float* __restrict__ W2,
        const float* __restrict__ b2, const int* __restrict__ task_id,
        const int* __restrict__ action, float* __restrict__ out,
        const int* __restrict__ wsi) {
    __shared__ float tile[MT][D_];   // 32 KB; xs tile, then reused as h tile
    __shared__ int sidx[MT];

    int bid = blockIdx.x;
    if (bid >= wsi[0]) return;
    int code = wsi[50 + bid];
    int t = code >> 16, kt = code & 0xffff;
    int off0 = wsi[17 + t], off1 = wsi[17 + t + 1];
    int base = off0 + kt * MT;
    int rows = off1 - base; if (rows > MT) rows = MT;

    int tid = threadIdx.x;
    if (tid < MT) sidx[tid] = (tid < rows) ? wsi[256 + base + tid] : -1;
    __syncthreads();

    // stage xs tile: thread = column d (0..511)
    for (int i = 0; i < MT; ++i) {
        int b = sidx[i];
        tile[i][tid] = (b >= 0) ? xs[(size_t)b * D_ + tid] : 0.f;
    }
    __syncthreads();

    // fc1 GEMM: thread owns column j = tid of H, all MT rows
    const float* w1p = W1 + (size_t)t * D_ * H_ + tid;
    float acc[MT];
#pragma unroll
    for (int i = 0; i < MT; ++i) acc[i] = 0.f;

    for (int d = 0; d < D_; d += 4) {
        float w0 = w1p[(size_t)(d + 0) * H_];
        float w1v = w1p[(size_t)(d + 1) * H_];
        float w2v = w1p[(size_t)(d + 2) * H_];
        float w3v = w1p[(size_t)(d + 3) * H_];
#pragma unroll
        for (int i = 0; i < MT; ++i) {
            float4 x = *(const float4*)&tile[i][d];   // wave-broadcast read
            float a0 = fmaf(x.x, w0, acc[i]);
            a0 = fmaf(x.y, w1v, a0);
            a0 = fmaf(x.z, w2v, a0);
            acc[i] = fmaf(x.w, w3v, a0);
        }
    }
    __syncthreads();

    // bias + relu -> h tile (reuse LDS)
    float b1v = b1[t * H_ + tid];
#pragma unroll
    for (int i = 0; i < MT; ++i) {
        float h = acc[i] + b1v;
        tile[i][tid] = h > 0.f ? h : 0.f;
    }
    __syncthreads();

    // fc2 + softmax: group g = tid/32 handles sample g; 32 lanes split H
    int g = tid >> 5, l = tid & 31;
    float lg[A_];
#pragma unroll
    for (int a = 0; a < A_; ++a) lg[a] = 0.f;
    const float* w2base = W2 + (size_t)t * H_ * A_;
    for (int hh = l; hh < H_; hh += 32) {
        float hv = tile[g][hh];
        const float* wrow = w2base + (size_t)hh * A_;
#pragma unroll
        for (int a = 0; a < A_; ++a) lg[a] = fmaf(hv, wrow[a], lg[a]);
    }
#pragma unroll
    for (int a = 0; a < A_; ++a) {
        lg[a] += __shfl_down(lg[a], 16, 32);
        lg[a] += __shfl_down(lg[a], 8, 32);
        lg[a] += __shfl_down(lg[a], 4, 32);
        lg[a] += __shfl_down(lg[a], 2, 32);
        lg[a] += __shfl_down(lg[a], 1, 32);
    }

    if (l == 0 && g < rows) {
        int b = sidx[g];
        float logits[A_];
        float m = -1e30f;
#pragma unroll
        for (int a = 0; a < A_; ++a) {
            logits[a] = lg[a] + b2[t * A_ + a];
            m = fmaxf(m, logits[a]);
        }
        float S = 0.f, sle = 0.f;
#pragma unroll
        for (int a = 0; a < A_; ++a) {
            float e = expf(logits[a] - m);
            S += e;
            sle += logits[a] * e;
        }
        float logZ = m + logf(S);
        int as = action[b];
        out[b] = (float)as;                    // action echo
        out[B_ + b] = logits[as] - logZ;       // log_pi_a
        out[2 * B_ + b] = logZ - sle / S;      // entropy
    }
}

extern "C" void kernel_launch(void* const* d_in, const int* in_sizes, int n_in,
                              void* d_out, int out_size, void* d_ws, size_t ws_size,
                              hipStream_t stream) {
    const float* xs = (const float*)d_in[0];
    const float* W1 = (const float*)d_in[1];
    const float* b1 = (const float*)d_in[2];
    const float* W2 = (const float*)d_in[3];
    const float* b2 = (const float*)d_in[4];
    const int* task_id = (const int*)d_in[5];
    const int* action = (const int*)d_in[6];
    float* out = (float*)d_out;
    int* wsi = (int*)d_ws;

    nk_init<<<1, 64, 0, stream>>>(wsi);
    nk_count<<<(B_ + 255) / 256, 256, 0, stream>>>(task_id, wsi);
    nk_plan<<<1, 1, 0, stream>>>(wsi);
    nk_scatter<<<(B_ + 255) / 256, 256, 0, stream>>>(task_id, wsi);
    nk_main<<<MAXTILES, 512, 0, stream>>>(xs, W1, b1, W2, b2, task_id, action, out, wsi);
}

// Round 2
// 52.895 us; speedup vs baseline: 2.0096x; 2.0096x over previous
//
#include <hip/hip_runtime.h>
#include <math.h>

#define B_ 2048
#define D_ 512
#define H_ 512
#define A_ 18
#define T_ 16
#define MT 16
#define MAXTILES 144

typedef __attribute__((ext_vector_type(8))) short short8;
typedef __attribute__((ext_vector_type(4))) float f32x4;

// ws layout (ints at base):
// [0] ntiles | [1..17) counts | [17..34) offsets[T+1] | [34..50) cursor
// [50..194) tiles (t<<16|k) | [256..2304) order[B]
// bytes: XSB_OFF=16384 xs_sorted bf16 [B][D] (2MB)
//        HB_OFF = 16384+2MB  h bf16 [B][H] (2MB)
//        W1T_OFF= 16384+4MB  W1T bf16 [T][H][D] (8MB)
#define XSB_OFF 16384
#define HB_OFF  (16384 + 2*1024*1024)
#define W1T_OFF (16384 + 4*1024*1024)
#define WS_NEED (16384 + 12*1024*1024)

__device__ __forceinline__ unsigned short f2bf(float f) {
    union { float f; unsigned int u; } v; v.f = f;
    unsigned int u = v.u;
    unsigned int r = (u + 0x7fffu + ((u >> 16) & 1u)) >> 16;
    return (unsigned short)r;
}
__device__ __forceinline__ float bf2f(unsigned short h) {
    union { unsigned int u; float f; } v; v.u = ((unsigned int)h) << 16;
    return v.f;
}

// ---------------- new path ----------------

__global__ __launch_bounds__(512) void nk_sort(const int* __restrict__ task_id,
                                               int* __restrict__ wsi) {
    __shared__ int cnt[T_], cur[T_], soff[T_ + 1];
    int tid = threadIdx.x;
    if (tid < T_) { cnt[tid] = 0; cur[tid] = 0; }
    __syncthreads();
    for (int b = tid; b < B_; b += 512) atomicAdd(&cnt[task_id[b]], 1);
    __syncthreads();
    if (tid == 0) {
        int off = 0, tot = 0;
        for (int t = 0; t < T_; ++t) {
            soff[t] = off; wsi[17 + t] = off;
            int nt = (cnt[t] + MT - 1) / MT;
            for (int k = 0; k < nt; ++k) wsi[50 + tot++] = (t << 16) | k;
            off += cnt[t];
        }
        soff[T_] = off; wsi[17 + T_] = off; wsi[0] = tot;
    }
    __syncthreads();
    for (int b = tid; b < B_; b += 512) {
        int t = task_id[b];
        int pos = atomicAdd(&cur[t], 1);
        wsi[256 + soff[t] + pos] = b;
    }
}

__global__ __launch_bounds__(256) void nk_gather(const float* __restrict__ xs,
                                                 unsigned short* __restrict__ xs_b,
                                                 const int* __restrict__ wsi) {
    int idx = blockIdx.x * 256 + threadIdx.x;   // 262144 total
    int r = idx >> 7;                            // 128 float4 per row
    int c = (idx & 127) << 2;
    int b = wsi[256 + r];
    float4 x = *(const float4*)(xs + (size_t)b * D_ + c);
    unsigned short o[4] = { f2bf(x.x), f2bf(x.y), f2bf(x.z), f2bf(x.w) };
    *(uint2*)(xs_b + (size_t)r * D_ + c) = *(const uint2*)o;
}

__global__ __launch_bounds__(256) void nk_w1t(const float* __restrict__ W1,
                                              unsigned short* __restrict__ w1t) {
    __shared__ float tile[64][65];
    int t = blockIdx.z, d0 = blockIdx.y * 64, h0 = blockIdx.x * 64;
    int tid = threadIdx.x, cx = tid & 63, ry = tid >> 6;   // ry 0..3
    const float* src = W1 + ((size_t)t * D_ + d0) * H_ + h0;
#pragma unroll
    for (int i = 0; i < 16; ++i) {
        int row = i * 4 + ry;
        tile[row][cx] = src[(size_t)row * H_ + cx];
    }
    __syncthreads();
    unsigned short* dst = w1t + ((size_t)t * H_ + h0) * D_ + d0;
#pragma unroll
    for (int i = 0; i < 16; ++i) {
        int hr = i * 4 + ry;
        dst[(size_t)hr * D_ + cx] = f2bf(tile[cx][hr]);
    }
}

__global__ __launch_bounds__(256) void nk_gemm1(const unsigned short* __restrict__ xs_b,
                                                const unsigned short* __restrict__ w1t,
                                                const float* __restrict__ b1,
                                                unsigned short* __restrict__ h_b,
                                                const int* __restrict__ wsi) {
    int ntiles = wsi[0];
    int tile = blockIdx.x;
    if (tile >= ntiles) return;
    int code = wsi[50 + tile];
    int t = code >> 16, k = code & 0xffff;
    int off0 = wsi[17 + t], off1 = wsi[17 + t + 1];
    int rowbase = off0 + k * MT;
    int rows = off1 - rowbase; if (rows > MT) rows = MT;

    int tid = threadIdx.x, l = tid & 63, w = tid >> 6;
    int r15 = l & 15, kg = l >> 4;                 // k-group 0..3
    int col0 = blockIdx.y * 128 + w * 32;

    int arow = rowbase + r15; if (arow > B_ - 1) arow = B_ - 1;
    const unsigned short* ap = xs_b + (size_t)arow * D_ + kg * 8;
    const unsigned short* bp0 = w1t + (size_t)t * D_ * H_ + (size_t)(col0 + r15) * D_ + kg * 8;
    const unsigned short* bp1 = bp0 + (size_t)16 * D_;

    f32x4 acc0 = {0.f, 0.f, 0.f, 0.f}, acc1 = {0.f, 0.f, 0.f, 0.f};

    short8 areg[16];
#pragma unroll
    for (int ks = 0; ks < 16; ++ks) areg[ks] = *(const short8*)(ap + ks * 32);
#pragma unroll
    for (int ks = 0; ks < 16; ++ks) {
        short8 bf0 = *(const short8*)(bp0 + ks * 32);
        short8 bf1 = *(const short8*)(bp1 + ks * 32);
        acc0 = __builtin_amdgcn_mfma_f32_16x16x32_bf16(areg[ks], bf0, acc0, 0, 0, 0);
        acc1 = __builtin_amdgcn_mfma_f32_16x16x32_bf16(areg[ks], bf1, acc1, 0, 0, 0);
    }

#pragma unroll
    for (int j = 0; j < 4; ++j) {
        int rr = kg * 4 + j;                       // C row = (lane>>4)*4 + reg
        if (rr < rows) {
            int gr = rowbase + rr;
            int c0 = col0 + r15;                   // C col = lane&15
            float v0 = acc0[j] + b1[t * H_ + c0];
            v0 = v0 > 0.f ? v0 : 0.f;
            h_b[(size_t)gr * H_ + c0] = f2bf(v0);
            int c1 = col0 + 16 + r15;
            float v1 = acc1[j] + b1[t * H_ + c1];
            v1 = v1 > 0.f ? v1 : 0.f;
            h_b[(size_t)gr * H_ + c1] = f2bf(v1);
        }
    }
}

__global__ __launch_bounds__(512) void nk_fc2(const unsigned short* __restrict__ h_b,
                                              const float* __restrict__ W2,
                                              const float* __restrict__ b2,
                                              const int* __restrict__ action,
                                              float* __restrict__ out,
                                              const int* __restrict__ wsi) {
    int tid = threadIdx.x;
    int g = tid >> 5, lane = tid & 31;
    int r = blockIdx.x * 16 + g;                  // sorted row
    int t = 0;
#pragma unroll
    for (int i = 1; i < T_; ++i) if (r >= wsi[17 + i]) t = i;
    int b = wsi[256 + r];

    const unsigned short* hp = h_b + (size_t)r * H_;
    const float* w2p = W2 + (size_t)t * H_ * A_;
    float lg[A_];
#pragma unroll
    for (int a = 0; a < A_; ++a) lg[a] = 0.f;
    for (int hh = lane; hh < H_; hh += 32) {
        float hv = bf2f(hp[hh]);
        const float* wrow = w2p + (size_t)hh * A_;
#pragma unroll
        for (int a = 0; a < A_; ++a) lg[a] = fmaf(hv, wrow[a], lg[a]);
    }
#pragma unroll
    for (int a = 0; a < A_; ++a) {
        lg[a] += __shfl_down(lg[a], 16, 32);
        lg[a] += __shfl_down(lg[a], 8, 32);
        lg[a] += __shfl_down(lg[a], 4, 32);
        lg[a] += __shfl_down(lg[a], 2, 32);
        lg[a] += __shfl_down(lg[a], 1, 32);
    }
    if (lane == 0) {
        float logits[A_];
        float m = -1e30f;
#pragma unroll
        for (int a = 0; a < A_; ++a) {
            logits[a] = lg[a] + b2[t * A_ + a];
            m = fmaxf(m, logits[a]);
        }
        float S = 0.f, sle = 0.f;
#pragma unroll
        for (int a = 0; a < A_; ++a) {
            float e = expf(logits[a] - m);
            S += e;
            sle += logits[a] * e;
        }
        float logZ = m + logf(S);
        int as = action[b];
        out[b] = (float)as;
        out[B_ + b] = logits[as] - logZ;
        out[2 * B_ + b] = logZ - sle / S;
    }
}

// ---------------- fallback path (round-1 kernels, known-good) ----------------

__global__ void nk_init(int* wsi) { int i = threadIdx.x; if (i < 50) wsi[i] = 0; }

__global__ void nk_count(const int* task_id, int* wsi) {
    int b = blockIdx.x * blockDim.x + threadIdx.x;
    if (b < B_) atomicAdd(&wsi[1 + task_id[b]], 1);
}

__global__ void nk_plan(int* wsi) {
    int off = 0, tot = 0;
    for (int t = 0; t < T_; ++t) {
        wsi[17 + t] = off;
        int cnt = wsi[1 + t];
        int nt = (cnt + MT - 1) / MT;
        for (int k = 0; k < nt; ++k) wsi[50 + tot++] = (t << 16) | k;
        off += cnt;
    }
    wsi[17 + T_] = off;
    wsi[0] = tot;
}

__global__ void nk_scatter(const int* task_id, int* wsi) {
    int b = blockIdx.x * blockDim.x + threadIdx.x;
    if (b < B_) {
        int t = task_id[b];
        int pos = atomicAdd(&wsi[34 + t], 1);
        wsi[256 + wsi[17 + t] + pos] = b;
    }
}

__global__ __launch_bounds__(512) void nk_main(
        const float* __restrict__ xs, const float* __restrict__ W1,
        const float* __restrict__ b1, const float* __restrict__ W2,
        const float* __restrict__ b2, const int* __restrict__ task_id,
        const int* __restrict__ action, float* __restrict__ out,
        const int* __restrict__ wsi) {
    __shared__ float tile[MT][D_];
    __shared__ int sidx[MT];
    int bid = blockIdx.x;
    if (bid >= wsi[0]) return;
    int code = wsi[50 + bid];
    int t = code >> 16, kt = code & 0xffff;
    int off0 = wsi[17 + t], off1 = wsi[17 + t + 1];
    int base = off0 + kt * MT;
    int rows = off1 - base; if (rows > MT) rows = MT;
    int tid = threadIdx.x;
    if (tid < MT) sidx[tid] = (tid < rows) ? wsi[256 + base + tid] : -1;
    __syncthreads();
    for (int i = 0; i < MT; ++i) {
        int b = sidx[i];
        tile[i][tid] = (b >= 0) ? xs[(size_t)b * D_ + tid] : 0.f;
    }
    __syncthreads();
    const float* w1p = W1 + (size_t)t * D_ * H_ + tid;
    float acc[MT];
#pragma unroll
    for (int i = 0; i < MT; ++i) acc[i] = 0.f;
    for (int d = 0; d < D_; d += 4) {
        float w0 = w1p[(size_t)(d + 0) * H_];
        float w1v = w1p[(size_t)(d + 1) * H_];
        float w2v = w1p[(size_t)(d + 2) * H_];
        float w3v = w1p[(size_t)(d + 3) * H_];
#pragma unroll
        for (int i = 0; i < MT; ++i) {
            float4 x = *(const float4*)&tile[i][d];
            float a0 = fmaf(x.x, w0, acc[i]);
            a0 = fmaf(x.y, w1v, a0);
            a0 = fmaf(x.z, w2v, a0);
            acc[i] = fmaf(x.w, w3v, a0);
        }
    }
    __syncthreads();
    float b1v = b1[t * H_ + tid];
#pragma unroll
    for (int i = 0; i < MT; ++i) {
        float h = acc[i] + b1v;
        tile[i][tid] = h > 0.f ? h : 0.f;
    }
    __syncthreads();
    int g = tid >> 5, l = tid & 31;
    float lg[A_];
#pragma unroll
    for (int a = 0; a < A_; ++a) lg[a] = 0.f;
    const float* w2base = W2 + (size_t)t * H_ * A_;
    for (int hh = l; hh < H_; hh += 32) {
        float hv = tile[g][hh];
        const float* wrow = w2base + (size_t)hh * A_;
#pragma unroll
        for (int a = 0; a < A_; ++a) lg[a] = fmaf(hv, wrow[a], lg[a]);
    }
#pragma unroll
    for (int a = 0; a < A_; ++a) {
        lg[a] += __shfl_down(lg[a], 16, 32);
        lg[a] += __shfl_down(lg[a], 8, 32);
        lg[a] += __shfl_down(lg[a], 4, 32);
        lg[a] += __shfl_down(lg[a], 2, 32);
        lg[a] += __shfl_down(lg[a], 1, 32);
    }
    if (l == 0 && g < rows) {
        int b = sidx[g];
        float logits[A_];
        float m = -1e30f;
#pragma unroll
        for (int a = 0; a < A_; ++a) {
            logits[a] = lg[a] + b2[t * A_ + a];
            m = fmaxf(m, logits[a]);
        }
        float S = 0.f, sle = 0.f;
#pragma unroll
        for (int a = 0; a < A_; ++a) {
            float e = expf(logits[a] - m);
            S += e;
            sle += logits[a] * e;
        }
        float logZ = m + logf(S);
        int as = action[b];
        out[b] = (float)as;
        out[B_ + b] = logits[as] - logZ;
        out[2 * B_ + b] = logZ - sle / S;
    }
}

extern "C" void kernel_launch(void* const* d_in, const int* in_sizes, int n_in,
                              void* d_out, int out_size, void* d_ws, size_t ws_size,
                              hipStream_t stream) {
    const float* xs = (const float*)d_in[0];
    const float* W1 = (const float*)d_in[1];
    const float* b1 = (const float*)d_in[2];
    const float* W2 = (const float*)d_in[3];
    const float* b2 = (const float*)d_in[4];
    const int* task_id = (const int*)d_in[5];
    const int* action = (const int*)d_in[6];
    float* out = (float*)d_out;
    int* wsi = (int*)d_ws;

    if (ws_size >= WS_NEED) {
        unsigned char* wsb = (unsigned char*)d_ws;
        unsigned short* xs_b = (unsigned short*)(wsb + XSB_OFF);
        unsigned short* h_b  = (unsigned short*)(wsb + HB_OFF);
        unsigned short* w1t  = (unsigned short*)(wsb + W1T_OFF);

        nk_sort<<<1, 512, 0, stream>>>(task_id, wsi);
        nk_gather<<<1024, 256, 0, stream>>>(xs, xs_b, wsi);
        nk_w1t<<<dim3(8, 8, T_), 256, 0, stream>>>(W1, w1t);
        nk_gemm1<<<dim3(MAXTILES, 4), 256, 0, stream>>>(xs_b, w1t, b1, h_b, wsi);
        nk_fc2<<<B_ / 16, 512, 0, stream>>>(h_b, W2, b2, action, out, wsi);
    } else {
        nk_init<<<1, 64, 0, stream>>>(wsi);
        nk_count<<<(B_ + 255) / 256, 256, 0, stream>>>(task_id, wsi);
        nk_plan<<<1, 1, 0, stream>>>(wsi);
        nk_scatter<<<(B_ + 255) / 256, 256, 0, stream>>>(task_id, wsi);
        nk_main<<<MAXTILES, 512, 0, stream>>>(xs, W1, b1, W2, b2, task_id, action, out, wsi);
    }
}